// Round 2
// baseline (343.016 us; speedup 1.0000x reference)
//
#include <hip/hip_runtime.h>

#define DEV __device__ __forceinline__

using bf16x8 = __attribute__((ext_vector_type(8))) __bf16;
using f32x4  = __attribute__((ext_vector_type(4))) float;
typedef unsigned int u32;
typedef unsigned short u16;
typedef unsigned long long u64;

static constexpr int Bb = 4, Ss = 1024, Ee = 1024, Hh = 16, Dd = 64, Ff = 4096;
static constexpr int Mm = Bb * Ss; // 4096 rows

// ---------- helpers ----------
DEV u16 f2bf(float f) {                 // fp32 -> bf16 RNE (finite inputs)
  union { float f; u32 u; } v; v.f = f;
  u32 r = v.u + 0x7fffu + ((v.u >> 16) & 1u);
  return (u16)(r >> 16);
}

DEV void gload16(const void* g, void* lds) {   // async global->LDS, 16B/lane
  __builtin_amdgcn_global_load_lds(
      (const __attribute__((address_space(1))) void*)(u64)g,
      (__attribute__((address_space(3))) void*)(u32)(u64)lds,
      16, 0, 0);
}

DEV float gelu_tanh(float x) {          // gelu_new (tanh approx)
  float x3 = x * x * x;
  float t  = tanhf(0.7978845608028654f * (x + 0.044715f * x3));
  return 0.5f * x * (1.0f + t);
}

// XOR-swizzle for [R][64] bf16 LDS tiles: spreads 128B-stride rows across banks
DEV int swz(int row, int col) { return row * 64 + (col ^ ((row & 7) << 3)); }

// ---------- fp32 -> bf16 convert (8 elems/thread) ----------
__global__ __launch_bounds__(256) void cvt_bf16(const float* __restrict__ in,
                                                u16* __restrict__ out, int n) {
  int i = (blockIdx.x * 256 + threadIdx.x) * 8;
  if (i >= n) return;
  float4 a = *(const float4*)(in + i);
  float4 b = *(const float4*)(in + i + 4);
  uint4 o;
  o.x = (u32)f2bf(a.x) | ((u32)f2bf(a.y) << 16);
  o.y = (u32)f2bf(a.z) | ((u32)f2bf(a.w) << 16);
  o.z = (u32)f2bf(b.x) | ((u32)f2bf(b.y) << 16);
  o.w = (u32)f2bf(b.z) | ((u32)f2bf(b.w) << 16);
  *(uint4*)(out + i) = o;
}

// ---------- LayerNorm: one row (1024) per block, fp32 in -> bf16 out ----------
__global__ __launch_bounds__(256) void ln_kernel(const float* __restrict__ x,
                                                 const float* __restrict__ scale,
                                                 const float* __restrict__ bias,
                                                 u16* __restrict__ h) {
  const int row = blockIdx.x, tid = threadIdx.x;
  const float4 v = ((const float4*)(x + (size_t)row * Ee))[tid];
  float s  = v.x + v.y + v.z + v.w;
  float ss = v.x * v.x + v.y * v.y + v.z * v.z + v.w * v.w;
  for (int m = 1; m < 64; m <<= 1) {
    s  += __shfl_xor(s, m, 64);
    ss += __shfl_xor(ss, m, 64);
  }
  __shared__ float red[8];
  const int w = tid >> 6, ln = tid & 63;
  if (ln == 0) { red[w * 2] = s; red[w * 2 + 1] = ss; }
  __syncthreads();
  s  = red[0] + red[2] + red[4] + red[6];
  ss = red[1] + red[3] + red[5] + red[7];
  const float mu   = s * (1.0f / Ee);
  const float var  = ss * (1.0f / Ee) - mu * mu;
  const float rstd = rsqrtf(var + 1e-5f);
  const float4 sc = ((const float4*)scale)[tid];
  const float4 bi = ((const float4*)bias)[tid];
  ushort4 o;
  o.x = f2bf((v.x - mu) * rstd * sc.x + bi.x);
  o.y = f2bf((v.y - mu) * rstd * sc.y + bi.y);
  o.z = f2bf((v.z - mu) * rstd * sc.z + bi.z);
  o.w = f2bf((v.w - mu) * rstd * sc.w + bi.w);
  ((ushort4*)(h + (size_t)row * Ee))[tid] = o;
}

// ---------- bf16 GEMM, C = A @ B^T (+epilogue). A[M,K], Bw[N,K] row-major ----
// 128x128 tile, BK=32, 4 waves (each 64x64), global_load_lds staging (m97).
// EPI: 0 = QKV split (+bias, q*0.125, scatter to [B,H,S,D] bf16)
//      1 = +bias +resid(fp32) -> fp32
//      2 = gelu(+bias) -> bf16
template <int EPI>
__global__ __launch_bounds__(256) void gemm_bt(
    const u16* __restrict__ A, const u16* __restrict__ Bw,
    const float* __restrict__ bias, const float* __restrict__ resid,
    float* __restrict__ outf, u16* __restrict__ outb,
    u16* __restrict__ q, u16* __restrict__ k, u16* __restrict__ v,
    int N, int K) {
  __shared__ u16 As[128 * 32];
  __shared__ u16 Bs[128 * 32];
  const int tid = threadIdx.x;
  const int w = tid >> 6, ln = tid & 63;
  const int lr = ln & 15, lg = ln >> 4;
  const int tm = blockIdx.y * 128, tn = blockIdx.x * 128;
  const int wr = (w >> 1) * 64, wc = (w & 1) * 64;

  f32x4 zero4 = {0.f, 0.f, 0.f, 0.f};
  f32x4 acc[4][4];
#pragma unroll
  for (int i = 0; i < 4; ++i)
#pragma unroll
    for (int j = 0; j < 4; ++j) acc[i][j] = zero4;

  // staging: 512 16B-granules per 8KB tile; thread covers granule tid and 256+tid
  const int srow = tid >> 2;        // 0..63
  const int scol = (tid & 3) * 8;   // 0/8/16/24
  const u16* aP = A  + (size_t)(tm + srow) * K + scol;
  const u16* bP = Bw + (size_t)(tn + srow) * K + scol;
  const size_t rstep = (size_t)64 * K;
  u16* aL0 = &As[w * 512];
  u16* aL1 = &As[2048 + w * 512];
  u16* bL0 = &Bs[w * 512];
  u16* bL1 = &Bs[2048 + w * 512];

  for (int k0 = 0; k0 < K; k0 += 32) {
    gload16(aP + k0, aL0);
    gload16(aP + rstep + k0, aL1);
    gload16(bP + k0, bL0);
    gload16(bP + rstep + k0, bL1);
    __syncthreads();
    bf16x8 af[4], bfrag[4];
#pragma unroll
    for (int mi = 0; mi < 4; ++mi)
      af[mi] = *(const bf16x8*)&As[(wr + mi * 16 + lr) * 32 + lg * 8];
#pragma unroll
    for (int ni = 0; ni < 4; ++ni)
      bfrag[ni] = *(const bf16x8*)&Bs[(wc + ni * 16 + lr) * 32 + lg * 8];
#pragma unroll
    for (int mi = 0; mi < 4; ++mi)
#pragma unroll
      for (int ni = 0; ni < 4; ++ni)
        acc[mi][ni] = __builtin_amdgcn_mfma_f32_16x16x32_bf16(
            af[mi], bfrag[ni], acc[mi][ni], 0, 0, 0);
    __syncthreads();
  }

#pragma unroll
  for (int mi = 0; mi < 4; ++mi) {
#pragma unroll
    for (int ni = 0; ni < 4; ++ni) {
      const int gc = tn + wc + ni * 16 + lr;
#pragma unroll
      for (int j = 0; j < 4; ++j) {
        const int gr = tm + wr + mi * 16 + lg * 4 + j;
        float val = acc[mi][ni][j] + bias[gc];
        if constexpr (EPI == 0) {
          const int which = gc >> 10, hh = (gc >> 6) & 15, dd = gc & 63;
          const int bb = gr >> 10, ss2 = gr & 1023;
          const size_t dst = ((size_t)(bb * 16 + hh) * 1024 + ss2) * 64 + dd;
          if (which == 0)      q[dst] = f2bf(val * 0.125f);   // 1/sqrt(64)
          else if (which == 1) k[dst] = f2bf(val);
          else                 v[dst] = f2bf(val);
        } else if constexpr (EPI == 1) {
          const size_t idx = (size_t)gr * N + gc;
          outf[idx] = val + resid[idx];
        } else {
          outb[(size_t)gr * N + gc] = f2bf(gelu_tanh(val));
        }
      }
    }
  }
}

// ---------- flash attention (no mask). Q pre-scaled. [B,H,S,D] bf16 in ------
// block = 64 q-rows of one (b,h); 4 waves, each 16 q-rows. KV tiles of 64.
__global__ __launch_bounds__(256) void attn_kernel(const u16* __restrict__ qg,
                                                   const u16* __restrict__ kg,
                                                   const u16* __restrict__ vg,
                                                   u16* __restrict__ ao) {
  __shared__ u16 Qs[64 * 64], Ks[64 * 64], Vt[64 * 64], Ps[64 * 64];
  const int tid = threadIdx.x;
  const int w = tid >> 6, ln = tid & 63;
  const int lr = ln & 15, lg = ln >> 4;
  const int bh = blockIdx.y;
  const int q0 = blockIdx.x * 64;
  const size_t head = (size_t)bh * (Ss * Dd);

  { // stage Q (swizzled)
    const u16* src = qg + head + (size_t)q0 * Dd;
#pragma unroll
    for (int i = 0; i < 2; ++i) {
      const int gi = i * 256 + tid, row = gi >> 3, g = gi & 7;
      *(uint4*)&Qs[row * 64 + ((g ^ (row & 7)) << 3)] = *(const uint4*)(src + gi * 8);
    }
  }

  f32x4 zero4 = {0.f, 0.f, 0.f, 0.f};
  f32x4 acc_o[4] = {zero4, zero4, zero4, zero4};
  float mrow[4] = {-1e30f, -1e30f, -1e30f, -1e30f};
  float lrow[4] = {0.f, 0.f, 0.f, 0.f};

  for (int kt = 0; kt < 16; ++kt) {
    __syncthreads();  // prev-tile Ks/Vt reads complete before restage
    const u16* ksrc = kg + head + (size_t)kt * 64 * Dd;
    const u16* vsrc = vg + head + (size_t)kt * 64 * Dd;
#pragma unroll
    for (int i = 0; i < 2; ++i) {
      const int gi = i * 256 + tid, row = gi >> 3, g = gi & 7;
      *(uint4*)&Ks[row * 64 + ((g ^ (row & 7)) << 3)] = *(const uint4*)(ksrc + gi * 8);
    }
#pragma unroll
    for (int i = 0; i < 2; ++i) {  // V transposed into Vt[d][kv] (swizzled)
      const int kv = i * 32 + (tid >> 3), d0 = (tid & 7) * 8;
      uint4 dv = *(const uint4*)(vsrc + (size_t)kv * Dd + d0);
      const u16* pv = (const u16*)&dv;
#pragma unroll
      for (int j = 0; j < 8; ++j) {
        const int dd = d0 + j;
        Vt[dd * 64 + (((kv >> 3) ^ (dd & 7)) << 3) + (kv & 7)] = pv[j];
      }
    }
    __syncthreads();

    // QK^T: S[q 16][kv 64] per wave
    bf16x8 aq[2];
#pragma unroll
    for (int kk = 0; kk < 2; ++kk)
      aq[kk] = *(const bf16x8*)&Qs[swz(w * 16 + lr, kk * 32 + lg * 8)];
    f32x4 sa[4];
#pragma unroll
    for (int kf = 0; kf < 4; ++kf) {
      f32x4 s = zero4;
#pragma unroll
      for (int kk = 0; kk < 2; ++kk) {
        bf16x8 bk = *(const bf16x8*)&Ks[swz(kf * 16 + lr, kk * 32 + lg * 8)];
        s = __builtin_amdgcn_mfma_f32_16x16x32_bf16(aq[kk], bk, s, 0, 0, 0);
      }
      sa[kf] = s;
    }

    // online softmax (row stats across kf frags + 16-lane col group)
#pragma unroll
    for (int j = 0; j < 4; ++j) {
      float mx = fmaxf(fmaxf(sa[0][j], sa[1][j]), fmaxf(sa[2][j], sa[3][j]));
      mx = fmaxf(mx, __shfl_xor(mx, 1, 64));
      mx = fmaxf(mx, __shfl_xor(mx, 2, 64));
      mx = fmaxf(mx, __shfl_xor(mx, 4, 64));
      mx = fmaxf(mx, __shfl_xor(mx, 8, 64));
      const float nm = fmaxf(mrow[j], mx);
      const float corr = __expf(mrow[j] - nm);
      mrow[j] = nm;
      float ssum = 0.f;
#pragma unroll
      for (int kf = 0; kf < 4; ++kf) {
        const float p = __expf(sa[kf][j] - nm);
        sa[kf][j] = p;
        ssum += p;
      }
      ssum += __shfl_xor(ssum, 1, 64);
      ssum += __shfl_xor(ssum, 2, 64);
      ssum += __shfl_xor(ssum, 4, 64);
      ssum += __shfl_xor(ssum, 8, 64);
      lrow[j] = lrow[j] * corr + ssum;
#pragma unroll
      for (int df = 0; df < 4; ++df) acc_o[df][j] *= corr;
    }

    // P -> LDS (bf16, swizzled)
#pragma unroll
    for (int kf = 0; kf < 4; ++kf)
#pragma unroll
      for (int j = 0; j < 4; ++j)
        Ps[swz(w * 16 + lg * 4 + j, kf * 16 + lr)] = f2bf(sa[kf][j]);

    __syncthreads();  // order P write -> P read (and keep compiler honest)

    // PV: O[q 16][d 64] += P @ V
    bf16x8 ap[2];
#pragma unroll
    for (int kk = 0; kk < 2; ++kk)
      ap[kk] = *(const bf16x8*)&Ps[swz(w * 16 + lr, kk * 32 + lg * 8)];
#pragma unroll
    for (int df = 0; df < 4; ++df) {
#pragma unroll
      for (int kk = 0; kk < 2; ++kk) {
        bf16x8 bv = *(const bf16x8*)&Vt[swz(df * 16 + lr, kk * 32 + lg * 8)];
        acc_o[df] = __builtin_amdgcn_mfma_f32_16x16x32_bf16(ap[kk], bv, acc_o[df], 0, 0, 0);
      }
    }
  }

  // epilogue: O/l -> attn_out [B,S,E] bf16
  const int b = bh >> 4, h = bh & 15;
#pragma unroll
  for (int df = 0; df < 4; ++df) {
#pragma unroll
    for (int j = 0; j < 4; ++j) {
      const int srow = q0 + w * 16 + lg * 4 + j;
      const int e = h * 64 + df * 16 + lr;
      ao[((size_t)b * Ss + srow) * Ee + e] = f2bf(acc_o[df][j] / lrow[j]);
    }
  }
}

// ---------- launcher ----------
extern "C" void kernel_launch(void* const* d_in, const int* in_sizes, int n_in,
                              void* d_out, int out_size, void* d_ws, size_t ws_size,
                              hipStream_t stream) {
  const float* x      = (const float*)d_in[0];
  const float* ln1_s  = (const float*)d_in[1];
  const float* ln1_b  = (const float*)d_in[2];
  const float* w_attn = (const float*)d_in[3];
  const float* b_attn = (const float*)d_in[4];
  const float* w_proj = (const float*)d_in[5];
  const float* b_proj = (const float*)d_in[6];
  const float* ln2_s  = (const float*)d_in[7];
  const float* ln2_b  = (const float*)d_in[8];
  const float* w_fc   = (const float*)d_in[9];
  const float* b_fc   = (const float*)d_in[10];
  const float* w_proj2= (const float*)d_in[11];
  const float* b_proj2= (const float*)d_in[12];
  float* out = (float*)d_out;

  char* base = (char*)d_ws;
  size_t off = 0;
  auto alloc = [&](size_t bytes) { char* p = base + off; off += bytes; return p; };
  u16* wA   = (u16*)alloc((size_t)3 * Ee * Ee * 2);  // 6 MB
  u16* wP   = (u16*)alloc((size_t)Ee * Ee * 2);      // 2 MB
  u16* wF   = (u16*)alloc((size_t)Ff * Ee * 2);      // 8 MB
  u16* wP2  = (u16*)alloc((size_t)Ee * Ff * 2);      // 8 MB
  u16* h1   = (u16*)alloc((size_t)Mm * Ee * 2);      // 8 MB (reused as h2)
  u16* qws  = (u16*)alloc((size_t)Mm * Ee * 2);      // 8 MB (q; mfc alias start)
  u16* kws  = (u16*)alloc((size_t)Mm * Ee * 2);      // 8 MB (k)
  u16* vws  = (u16*)alloc((size_t)Mm * Ee * 2);      // 8 MB (v)
  u16* aws  = (u16*)alloc((size_t)Mm * Ee * 2);      // 8 MB (attn out)
  float* x1 = (float*)alloc((size_t)Mm * Ee * 4);    // 16 MB
  u16* mfc  = qws;  // [4096,4096] bf16 aliases q/k/v/ao (all dead by then)

  // weights -> bf16 (every call; deterministic)
  cvt_bf16<<<3 * Ee * Ee / 2048, 256, 0, stream>>>(w_attn, wA, 3 * Ee * Ee);
  cvt_bf16<<<Ee * Ee / 2048, 256, 0, stream>>>(w_proj, wP, Ee * Ee);
  cvt_bf16<<<Ff * Ee / 2048, 256, 0, stream>>>(w_fc, wF, Ff * Ee);
  cvt_bf16<<<Ee * Ff / 2048, 256, 0, stream>>>(w_proj2, wP2, Ee * Ff);

  // LN1 -> h1
  ln_kernel<<<Mm, 256, 0, stream>>>(x, ln1_s, ln1_b, h1);
  // QKV GEMM: [4096,1024]@[1024,3072]^T -> q,k,v [B,H,S,D]
  gemm_bt<0><<<dim3(24, 32), 256, 0, stream>>>(h1, wA, b_attn, nullptr,
                                               nullptr, nullptr, qws, kws, vws,
                                               3 * Ee, Ee);
  // attention
  attn_kernel<<<dim3(16, 64), 256, 0, stream>>>(qws, kws, vws, aws);
  // proj + residual -> x1 (fp32)
  gemm_bt<1><<<dim3(8, 32), 256, 0, stream>>>(aws, wP, b_proj, x,
                                              x1, nullptr, nullptr, nullptr, nullptr,
                                              Ee, Ee);
  // LN2 -> h1 (as h2)
  ln_kernel<<<Mm, 256, 0, stream>>>(x1, ln2_s, ln2_b, h1);
  // fc + gelu -> mfc (bf16)
  gemm_bt<2><<<dim3(32, 32), 256, 0, stream>>>(h1, wF, b_fc, nullptr,
                                               nullptr, mfc, nullptr, nullptr, nullptr,
                                               Ff, Ee);
  // proj2 + residual -> out (fp32)
  gemm_bt<1><<<dim3(8, 32), 256, 0, stream>>>(mfc, wP2, b_proj2, x1,
                                              out, nullptr, nullptr, nullptr, nullptr,
                                              Ee, Ff);
}

// Round 3
// 285.283 us; speedup vs baseline: 1.2024x; 1.2024x over previous
//
#include <hip/hip_runtime.h>

#define DEV __device__ __forceinline__

using bf16x8 = __attribute__((ext_vector_type(8))) __bf16;
using f32x4  = __attribute__((ext_vector_type(4))) float;
typedef unsigned int u32;
typedef unsigned short u16;
typedef unsigned long long u64;

static constexpr int Bb = 4, Ss = 1024, Ee = 1024, Hh = 16, Dd = 64, Ff = 4096;
static constexpr int Mm = Bb * Ss; // 4096 rows

// ---------- helpers ----------
DEV u16 f2bf(float f) {                 // fp32 -> bf16 RNE (finite inputs)
  union { float f; u32 u; } v; v.f = f;
  u32 r = v.u + 0x7fffu + ((v.u >> 16) & 1u);
  return (u16)(r >> 16);
}

DEV void gload16(const void* g, void* lds) {   // async global->LDS, 16B/lane
  __builtin_amdgcn_global_load_lds(
      (const __attribute__((address_space(1))) void*)(u64)g,
      (__attribute__((address_space(3))) void*)(u32)(u64)lds,
      16, 0, 0);
}

DEV float gelu_tanh(float x) {          // gelu_new (tanh approx)
  float x3 = x * x * x;
  float t  = tanhf(0.7978845608028654f * (x + 0.044715f * x3));
  return 0.5f * x * (1.0f + t);
}

// XOR-swizzle for [R][64] bf16 LDS tiles (attention): 16B-slot ^= row&7
DEV int swz(int row, int col) { return row * 64 + (col ^ ((row & 7) << 3)); }

// ---------- fp32 -> bf16 convert (8 elems/thread) ----------
__global__ __launch_bounds__(256) void cvt_bf16(const float* __restrict__ in,
                                                u16* __restrict__ out, int n) {
  int i = (blockIdx.x * 256 + threadIdx.x) * 8;
  if (i >= n) return;
  float4 a = *(const float4*)(in + i);
  float4 b = *(const float4*)(in + i + 4);
  uint4 o;
  o.x = (u32)f2bf(a.x) | ((u32)f2bf(a.y) << 16);
  o.y = (u32)f2bf(a.z) | ((u32)f2bf(a.w) << 16);
  o.z = (u32)f2bf(b.x) | ((u32)f2bf(b.y) << 16);
  o.w = (u32)f2bf(b.z) | ((u32)f2bf(b.w) << 16);
  *(uint4*)(out + i) = o;
}

// ---------- LayerNorm: one row (1024) per block, fp32 in -> bf16 out ----------
__global__ __launch_bounds__(256) void ln_kernel(const float* __restrict__ x,
                                                 const float* __restrict__ scale,
                                                 const float* __restrict__ bias,
                                                 u16* __restrict__ h) {
  const int row = blockIdx.x, tid = threadIdx.x;
  const float4 v = ((const float4*)(x + (size_t)row * Ee))[tid];
  float s  = v.x + v.y + v.z + v.w;
  float ss = v.x * v.x + v.y * v.y + v.z * v.z + v.w * v.w;
  for (int m = 1; m < 64; m <<= 1) {
    s  += __shfl_xor(s, m, 64);
    ss += __shfl_xor(ss, m, 64);
  }
  __shared__ float red[8];
  const int w = tid >> 6, ln = tid & 63;
  if (ln == 0) { red[w * 2] = s; red[w * 2 + 1] = ss; }
  __syncthreads();
  s  = red[0] + red[2] + red[4] + red[6];
  ss = red[1] + red[3] + red[5] + red[7];
  const float mu   = s * (1.0f / Ee);
  const float var  = ss * (1.0f / Ee) - mu * mu;
  const float rstd = rsqrtf(var + 1e-5f);
  const float4 sc = ((const float4*)scale)[tid];
  const float4 bi = ((const float4*)bias)[tid];
  ushort4 o;
  o.x = f2bf((v.x - mu) * rstd * sc.x + bi.x);
  o.y = f2bf((v.y - mu) * rstd * sc.y + bi.y);
  o.z = f2bf((v.z - mu) * rstd * sc.z + bi.z);
  o.w = f2bf((v.w - mu) * rstd * sc.w + bi.w);
  ((ushort4*)(h + (size_t)row * Ee))[tid] = o;
}

// ---------- bf16 GEMM v2: C = A @ B^T (+epilogue). A[M,K], Bw[N,K] row-major -
// 128x128 tile, BK=32, 4 waves. 3-deep ring-buffer staging with counted
// vmcnt(4) (T4), slot-swizzled LDS (T2, via pre-swizzled global source),
// setprio around MFMA (T5), XCD-bijective block swizzle (T1).
// EPI: 0 = QKV split (+bias, q*0.125, scatter to [B,H,S,D] bf16)
//      1 = +bias +resid(fp32) -> fp32
//      2 = gelu(+bias) -> bf16
template <int EPI>
__global__ __launch_bounds__(256, 3) void gemm2(
    const u16* __restrict__ A, const u16* __restrict__ Bw,
    const float* __restrict__ bias, const float* __restrict__ resid,
    float* __restrict__ outf, u16* __restrict__ outb,
    u16* __restrict__ q, u16* __restrict__ k, u16* __restrict__ v,
    int N, int K) {
  __shared__ u16 As[3][128 * 32];   // 3 x 8KB
  __shared__ u16 Bs[3][128 * 32];   // 3 x 8KB  (48KB total)
  const int tid = threadIdx.x;
  const int w = tid >> 6, ln = tid & 63;
  const int lr = ln & 15, lg = ln >> 4;

  // XCD-aware bijective block swizzle (all grids here have nwg % 8 == 0)
  const int nwg = gridDim.x * gridDim.y;
  const int bid = blockIdx.y * gridDim.x + blockIdx.x;
  const int sid = (bid & 7) * (nwg >> 3) + (bid >> 3);
  const int bx = sid % gridDim.x, by = sid / gridDim.x;
  const int tm = by * 128, tn = bx * 128;
  const int wr = (w >> 1) * 64, wc = (w & 1) * 64;

  f32x4 zero4 = {0.f, 0.f, 0.f, 0.f};
  f32x4 acc[4][4];
#pragma unroll
  for (int i = 0; i < 4; ++i)
#pragma unroll
    for (int j = 0; j < 4; ++j) acc[i][j] = zero4;

  // staging: granule g0 = tid (rows 0..63), g1 = 256+tid (rows 64..127).
  // LDS dest is LINEAR (granule g at byte g*16); the 16B-slot swizzle
  // (slot ^= row&3) is applied on the GLOBAL source address instead
  // (rule: swizzle both-sides-or-neither with global_load_lds).
  const int r0 = tid >> 2, sl = tid & 3;
  const int cs = (sl ^ (r0 & 3)) * 8;   // (r0+64)&3 == r0&3, so same for g1
  const u16* aP0 = A  + (size_t)(tm + r0) * K + cs;
  const u16* aP1 = A  + (size_t)(tm + 64 + r0) * K + cs;
  const u16* bP0 = Bw + (size_t)(tn + r0) * K + cs;
  const u16* bP1 = Bw + (size_t)(tn + 64 + r0) * K + cs;

  auto STAGE = [&](int buf, int k0) {
    gload16(aP0 + k0, &As[buf][tid * 8]);
    gload16(aP1 + k0, &As[buf][(256 + tid) * 8]);
    gload16(bP0 + k0, &Bs[buf][tid * 8]);
    gload16(bP1 + k0, &Bs[buf][(256 + tid) * 8]);
  };

  const int nt = K >> 5;
  STAGE(0, 0);
  STAGE(1, 32);
  asm volatile("s_waitcnt vmcnt(4)" ::: "memory");  // tile0 landed; tile1 in flight
  __builtin_amdgcn_s_barrier();
  __builtin_amdgcn_sched_barrier(0);

  for (int t = 0; t < nt; ++t) {
    const int cur = t % 3;
    const bool more = (t + 2) < nt;
    if (more) STAGE((t + 2) % 3, (t + 2) << 5);   // prefetch 2 tiles ahead

    bf16x8 af[4], bb[4];
#pragma unroll
    for (int mi = 0; mi < 4; ++mi) {
      const int row = wr + mi * 16 + lr;
      af[mi] = *(const bf16x8*)&As[cur][row * 32 + ((lg ^ (row & 3)) << 3)];
    }
#pragma unroll
    for (int ni = 0; ni < 4; ++ni) {
      const int row = wc + ni * 16 + lr;
      bb[ni] = *(const bf16x8*)&Bs[cur][row * 32 + ((lg ^ (row & 3)) << 3)];
    }
    __builtin_amdgcn_s_setprio(1);
#pragma unroll
    for (int mi = 0; mi < 4; ++mi)
#pragma unroll
      for (int ni = 0; ni < 4; ++ni)
        acc[mi][ni] = __builtin_amdgcn_mfma_f32_16x16x32_bf16(
            af[mi], bb[ni], acc[mi][ni], 0, 0, 0);
    __builtin_amdgcn_s_setprio(0);
    __builtin_amdgcn_sched_barrier(0);
    // counted drain: only tile t+1's 4 loads must have landed (never 0 mid-loop)
    if (more) asm volatile("s_waitcnt vmcnt(4)" ::: "memory");
    else      asm volatile("s_waitcnt vmcnt(0)" ::: "memory");
    __builtin_amdgcn_s_barrier();
    __builtin_amdgcn_sched_barrier(0);
  }

#pragma unroll
  for (int mi = 0; mi < 4; ++mi) {
#pragma unroll
    for (int ni = 0; ni < 4; ++ni) {
      const int gc = tn + wc + ni * 16 + lr;
#pragma unroll
      for (int j = 0; j < 4; ++j) {
        const int gr = tm + wr + mi * 16 + lg * 4 + j;
        float val = acc[mi][ni][j] + bias[gc];
        if constexpr (EPI == 0) {
          const int which = gc >> 10, hh = (gc >> 6) & 15, dd = gc & 63;
          const int bb2 = gr >> 10, ss2 = gr & 1023;
          const size_t dst = ((size_t)(bb2 * 16 + hh) * 1024 + ss2) * 64 + dd;
          if (which == 0)      q[dst] = f2bf(val * 0.125f);   // 1/sqrt(64)
          else if (which == 1) k[dst] = f2bf(val);
          else                 v[dst] = f2bf(val);
        } else if constexpr (EPI == 1) {
          const size_t idx = (size_t)gr * N + gc;
          outf[idx] = val + resid[idx];
        } else {
          outb[(size_t)gr * N + gc] = f2bf(gelu_tanh(val));
        }
      }
    }
  }
}

// ---------- flash attention (no mask). Q pre-scaled. [B,H,S,D] bf16 in ------
// block = 64 q-rows of one (b,h); 4 waves, each 16 q-rows. KV tiles of 64.
__global__ __launch_bounds__(256) void attn_kernel(const u16* __restrict__ qg,
                                                   const u16* __restrict__ kg,
                                                   const u16* __restrict__ vg,
                                                   u16* __restrict__ ao) {
  __shared__ u16 Qs[64 * 64], Ks[64 * 64], Vt[64 * 64], Ps[64 * 64];
  const int tid = threadIdx.x;
  const int w = tid >> 6, ln = tid & 63;
  const int lr = ln & 15, lg = ln >> 4;
  const int bh = blockIdx.y;
  const int q0 = blockIdx.x * 64;
  const size_t head = (size_t)bh * (Ss * Dd);

  { // stage Q (swizzled)
    const u16* src = qg + head + (size_t)q0 * Dd;
#pragma unroll
    for (int i = 0; i < 2; ++i) {
      const int gi = i * 256 + tid, row = gi >> 3, g = gi & 7;
      *(uint4*)&Qs[row * 64 + ((g ^ (row & 7)) << 3)] = *(const uint4*)(src + gi * 8);
    }
  }

  f32x4 zero4 = {0.f, 0.f, 0.f, 0.f};
  f32x4 acc_o[4] = {zero4, zero4, zero4, zero4};
  float mrow[4] = {-1e30f, -1e30f, -1e30f, -1e30f};
  float lrow[4] = {0.f, 0.f, 0.f, 0.f};

  for (int kt = 0; kt < 16; ++kt) {
    __syncthreads();  // prev-tile Ks/Vt reads complete before restage
    const u16* ksrc = kg + head + (size_t)kt * 64 * Dd;
    const u16* vsrc = vg + head + (size_t)kt * 64 * Dd;
#pragma unroll
    for (int i = 0; i < 2; ++i) {
      const int gi = i * 256 + tid, row = gi >> 3, g = gi & 7;
      *(uint4*)&Ks[row * 64 + ((g ^ (row & 7)) << 3)] = *(const uint4*)(ksrc + gi * 8);
    }
#pragma unroll
    for (int i = 0; i < 2; ++i) {  // V transposed into Vt[d][kv] (swizzled)
      const int kv = i * 32 + (tid >> 3), d0 = (tid & 7) * 8;
      uint4 dv = *(const uint4*)(vsrc + (size_t)kv * Dd + d0);
      const u16* pv = (const u16*)&dv;
#pragma unroll
      for (int j = 0; j < 8; ++j) {
        const int dd = d0 + j;
        Vt[dd * 64 + (((kv >> 3) ^ (dd & 7)) << 3) + (kv & 7)] = pv[j];
      }
    }
    __syncthreads();

    // QK^T: S[q 16][kv 64] per wave
    bf16x8 aq[2];
#pragma unroll
    for (int kk = 0; kk < 2; ++kk)
      aq[kk] = *(const bf16x8*)&Qs[swz(w * 16 + lr, kk * 32 + lg * 8)];
    f32x4 sa[4];
#pragma unroll
    for (int kf = 0; kf < 4; ++kf) {
      f32x4 s = zero4;
#pragma unroll
      for (int kk = 0; kk < 2; ++kk) {
        bf16x8 bk = *(const bf16x8*)&Ks[swz(kf * 16 + lr, kk * 32 + lg * 8)];
        s = __builtin_amdgcn_mfma_f32_16x16x32_bf16(aq[kk], bk, s, 0, 0, 0);
      }
      sa[kf] = s;
    }

    // online softmax (row stats across kf frags + 16-lane col group)
#pragma unroll
    for (int j = 0; j < 4; ++j) {
      float mx = fmaxf(fmaxf(sa[0][j], sa[1][j]), fmaxf(sa[2][j], sa[3][j]));
      mx = fmaxf(mx, __shfl_xor(mx, 1, 64));
      mx = fmaxf(mx, __shfl_xor(mx, 2, 64));
      mx = fmaxf(mx, __shfl_xor(mx, 4, 64));
      mx = fmaxf(mx, __shfl_xor(mx, 8, 64));
      const float nm = fmaxf(mrow[j], mx);
      const float corr = __expf(mrow[j] - nm);
      mrow[j] = nm;
      float ssum = 0.f;
#pragma unroll
      for (int kf = 0; kf < 4; ++kf) {
        const float p = __expf(sa[kf][j] - nm);
        sa[kf][j] = p;
        ssum += p;
      }
      ssum += __shfl_xor(ssum, 1, 64);
      ssum += __shfl_xor(ssum, 2, 64);
      ssum += __shfl_xor(ssum, 4, 64);
      ssum += __shfl_xor(ssum, 8, 64);
      lrow[j] = lrow[j] * corr + ssum;
#pragma unroll
      for (int df = 0; df < 4; ++df) acc_o[df][j] *= corr;
    }

    // P -> LDS (bf16, swizzled)
#pragma unroll
    for (int kf = 0; kf < 4; ++kf)
#pragma unroll
      for (int j = 0; j < 4; ++j)
        Ps[swz(w * 16 + lg * 4 + j, kf * 16 + lr)] = f2bf(sa[kf][j]);

    __syncthreads();  // order P write -> P read (and keep compiler honest)

    // PV: O[q 16][d 64] += P @ V
    bf16x8 ap[2];
#pragma unroll
    for (int kk = 0; kk < 2; ++kk)
      ap[kk] = *(const bf16x8*)&Ps[swz(w * 16 + lr, kk * 32 + lg * 8)];
#pragma unroll
    for (int df = 0; df < 4; ++df) {
#pragma unroll
      for (int kk = 0; kk < 2; ++kk) {
        bf16x8 bv = *(const bf16x8*)&Vt[swz(df * 16 + lr, kk * 32 + lg * 8)];
        acc_o[df] = __builtin_amdgcn_mfma_f32_16x16x32_bf16(ap[kk], bv, acc_o[df], 0, 0, 0);
      }
    }
  }

  // epilogue: O/l -> attn_out [B,S,E] bf16
  const int b = bh >> 4, h = bh & 15;
#pragma unroll
  for (int df = 0; df < 4; ++df) {
#pragma unroll
    for (int j = 0; j < 4; ++j) {
      const int srow = q0 + w * 16 + lg * 4 + j;
      const int e = h * 64 + df * 16 + lr;
      ao[((size_t)b * Ss + srow) * Ee + e] = f2bf(acc_o[df][j] / lrow[j]);
    }
  }
}

// ---------- launcher ----------
extern "C" void kernel_launch(void* const* d_in, const int* in_sizes, int n_in,
                              void* d_out, int out_size, void* d_ws, size_t ws_size,
                              hipStream_t stream) {
  const float* x      = (const float*)d_in[0];
  const float* ln1_s  = (const float*)d_in[1];
  const float* ln1_b  = (const float*)d_in[2];
  const float* w_attn = (const float*)d_in[3];
  const float* b_attn = (const float*)d_in[4];
  const float* w_proj = (const float*)d_in[5];
  const float* b_proj = (const float*)d_in[6];
  const float* ln2_s  = (const float*)d_in[7];
  const float* ln2_b  = (const float*)d_in[8];
  const float* w_fc   = (const float*)d_in[9];
  const float* b_fc   = (const float*)d_in[10];
  const float* w_proj2= (const float*)d_in[11];
  const float* b_proj2= (const float*)d_in[12];
  float* out = (float*)d_out;

  char* base = (char*)d_ws;
  size_t off = 0;
  auto alloc = [&](size_t bytes) { char* p = base + off; off += bytes; return p; };
  u16* wA   = (u16*)alloc((size_t)3 * Ee * Ee * 2);  // 6 MB
  u16* wP   = (u16*)alloc((size_t)Ee * Ee * 2);      // 2 MB
  u16* wF   = (u16*)alloc((size_t)Ff * Ee * 2);      // 8 MB
  u16* wP2  = (u16*)alloc((size_t)Ee * Ff * 2);      // 8 MB
  u16* h1   = (u16*)alloc((size_t)Mm * Ee * 2);      // 8 MB (reused as h2)
  u16* qws  = (u16*)alloc((size_t)Mm * Ee * 2);      // 8 MB (q; mfc alias start)
  u16* kws  = (u16*)alloc((size_t)Mm * Ee * 2);      // 8 MB (k)
  u16* vws  = (u16*)alloc((size_t)Mm * Ee * 2);      // 8 MB (v)
  u16* aws  = (u16*)alloc((size_t)Mm * Ee * 2);      // 8 MB (attn out)
  float* x1 = (float*)alloc((size_t)Mm * Ee * 4);    // 16 MB
  u16* mfc  = qws;  // [4096,4096] bf16 aliases q/k/v/ao (all dead by then)

  // weights -> bf16 (every call; deterministic)
  cvt_bf16<<<3 * Ee * Ee / 2048, 256, 0, stream>>>(w_attn, wA, 3 * Ee * Ee);
  cvt_bf16<<<Ee * Ee / 2048, 256, 0, stream>>>(w_proj, wP, Ee * Ee);
  cvt_bf16<<<Ff * Ee / 2048, 256, 0, stream>>>(w_fc, wF, Ff * Ee);
  cvt_bf16<<<Ee * Ff / 2048, 256, 0, stream>>>(w_proj2, wP2, Ee * Ff);

  // LN1 -> h1
  ln_kernel<<<Mm, 256, 0, stream>>>(x, ln1_s, ln1_b, h1);
  // QKV GEMM: [4096,1024]@[1024,3072]^T -> q,k,v [B,H,S,D]
  gemm2<0><<<dim3(24, 32), 256, 0, stream>>>(h1, wA, b_attn, nullptr,
                                             nullptr, nullptr, qws, kws, vws,
                                             3 * Ee, Ee);
  // attention
  attn_kernel<<<dim3(16, 64), 256, 0, stream>>>(qws, kws, vws, aws);
  // proj + residual -> x1 (fp32)
  gemm2<1><<<dim3(8, 32), 256, 0, stream>>>(aws, wP, b_proj, x,
                                            x1, nullptr, nullptr, nullptr, nullptr,
                                            Ee, Ee);
  // LN2 -> h1 (as h2)
  ln_kernel<<<Mm, 256, 0, stream>>>(x1, ln2_s, ln2_b, h1);
  // fc + gelu -> mfc (bf16)
  gemm2<2><<<dim3(32, 32), 256, 0, stream>>>(h1, wF, b_fc, nullptr,
                                             nullptr, mfc, nullptr, nullptr, nullptr,
                                             Ff, Ee);
  // proj2 + residual -> out (fp32)
  gemm2<1><<<dim3(8, 32), 256, 0, stream>>>(mfc, wP2, b_proj2, x1,
                                            out, nullptr, nullptr, nullptr, nullptr,
                                            Ee, Ff);
}